// Round 5
// baseline (555.579 us; speedup 1.0000x reference)
//
#include <hip/hip_runtime.h>
#include <hip/hip_bf16.h>

// ---------------------------------------------------------------------------
// MaskedSuperAttention (agent attention), B=4 N=16384 C=512 H=8 HD=64 NA=32
//   k_w_t        : W* f32 [k][n] -> Wt bf16 [n][k] row-major (for k_avp)
//   k_w_tile     : Wq/Wk/Wv -> wtl tiled-swizzled (for k_qkv gload_lds)
//   k_pack_a     : agent_tokens -> abf [h][32][64] bf16
//   k_qkv        : FUSED: reads x f32 directly (reg-staged cvt), 2-phase
//                  double-buffered pipeline, writes K (row), V (transposed),
//                  and computes q->agent softmax in-epilogue -> Qattn TILED.
//                  Q never touches HBM.
//   k_agent_part : split-K flash partials ; grid 2048
//   k_agent_comb : merge partials -> agent_v bf16
//   k_avp        : AVP = agent_v @ Wproj -> AVPt TILED
//   k_out        : out = (Qattn @ AVPt) * keymask ; gload_lds staging
// Tiled layout: tile = 128 rows x 64 k (16 KiB); byte(row,c8) =
//   base + row*128 + ((c8 ^ (row&7))<<4)   (c8 = 16B slot, 0..7)
// ---------------------------------------------------------------------------

typedef float  f32x4   __attribute__((ext_vector_type(4)));
typedef short  bf16x8  __attribute__((ext_vector_type(8)));
typedef unsigned short u16x4 __attribute__((ext_vector_type(4)));
typedef unsigned short u16x8 __attribute__((ext_vector_type(8)));

#define MFMA16(a, b, c) __builtin_amdgcn_mfma_f32_16x16x32_bf16((a), (b), (c), 0, 0, 0)

__device__ __forceinline__ unsigned short f2bf(float f) {
    unsigned u = __builtin_bit_cast(unsigned, f);
    u += 0x7FFFu + ((u >> 16) & 1u);        // RTNE
    return (unsigned short)(u >> 16);
}
__device__ __forceinline__ float bf2f(unsigned short h) {
    unsigned u = ((unsigned)h) << 16;
    return __builtin_bit_cast(float, u);
}
__device__ __forceinline__ void gl2lds16(const void* g, void* l) {
    __builtin_amdgcn_global_load_lds(
        (const __attribute__((address_space(1))) unsigned int*)g,
        (__attribute__((address_space(3))) unsigned int*)l, 16, 0, 0);
}

// ------------------------------- k_w_t --------------------------------------
// row-major transposed weights (k_avp needs Wproj^T). grid (16,16,4), block 256
__global__ __launch_bounds__(256) void k_w_t(const float* __restrict__ Wq,
                                             const float* __restrict__ Wk,
                                             const float* __restrict__ Wv,
                                             const float* __restrict__ Wp,
                                             unsigned short* __restrict__ Wt) {
    __shared__ float t[32][33];
    const int z = blockIdx.z;
    const float* src = (z == 0) ? Wq : (z == 1) ? Wk : (z == 2) ? Wv : Wp;
    unsigned short* dst = Wt + (size_t)z * 262144;
    const int k0 = blockIdx.y * 32, n0 = blockIdx.x * 32;
#pragma unroll
    for (int j = 0; j < 4; ++j) {
        int i = threadIdx.x + 256 * j;
        int ky = i >> 5, nx = i & 31;
        t[ky][nx] = src[(size_t)(k0 + ky) * 512 + n0 + nx];
    }
    __syncthreads();
#pragma unroll
    for (int j = 0; j < 4; ++j) {
        int i = threadIdx.x + 256 * j;
        int ny = i >> 5, kx = i & 31;
        dst[(size_t)(n0 + ny) * 512 + k0 + kx] = f2bf(t[kx][ny]);
    }
}

// ------------------------------- k_w_tile -----------------------------------
// Wq/Wk/Wv -> tiled-swizzled wtl: trio tile (nt,ks,mat) of [64 n][64 k], 8 KiB.
__global__ __launch_bounds__(256) void k_w_tile(const float* __restrict__ Wq,
                                                const float* __restrict__ Wk,
                                                const float* __restrict__ Wv,
                                                unsigned char* __restrict__ wtl) {
    const int ks = blockIdx.x, nt = blockIdx.y, mat = blockIdx.z;
    const float* src = (mat == 0) ? Wq : (mat == 1) ? Wk : Wv;
    const size_t dbase = ((size_t)((nt * 8 + ks) * 3 + mat)) * 8192;
    const int row = threadIdx.x & 63;
#pragma unroll
    for (int cc = 0; cc < 2; ++cc) {
        int c = (threadIdx.x >> 6) + cc * 4;
        u16x8 o;
#pragma unroll
        for (int j = 0; j < 8; ++j)
            o[j] = f2bf(src[(size_t)(ks * 64 + c * 8 + j) * 512 + nt * 64 + row]);
        *(u16x8*)(wtl + dbase + row * 128 + ((c ^ (row & 7)) << 4)) = o;
    }
}

// ------------------------------- k_pack_a -----------------------------------
__global__ __launch_bounds__(256) void k_pack_a(const float* __restrict__ at,
                                                unsigned short* __restrict__ abf) {
    int idx = threadIdx.x + blockIdx.x * 256;       // 0..16383
    int h = idx >> 11, ag = (idx >> 6) & 31, d = idx & 63;
    abf[idx] = f2bf(at[ag * 512 + h * 64 + d]);
}

// ------------------------------- k_qkv ---------------------------------------
// BM=128, BN=192 (Q64,K64,V64), BK=64, 4 waves 2x2, 2-phase dbuf pipeline.
// A reg-staged from x f32 (fused cvt); B via gl2lds of pre-swizzled tiles.
// Epilogue: acc -> LDS tiles; waves wn==1 store K,V coalesced; waves wn==0
// compute q->agent softmax (MFMA on LDS-transposed Q + agent frags) -> Qat.
// grid 4096 (XCD-swizzled), block 256.
__global__ __launch_bounds__(256) void k_qkv(const float* __restrict__ x,
                                             const unsigned char* __restrict__ wtl,
                                             const unsigned short* __restrict__ abf,
                                             unsigned char* __restrict__ Qat,
                                             unsigned short* __restrict__ Kbf,
                                             unsigned short* __restrict__ Vt) {
    __shared__ __align__(16) unsigned char As[2][16384];
    __shared__ __align__(16) unsigned char Bs[2][24576];
    const int tid = threadIdx.x, l = tid & 63, wid = tid >> 6;
    const int g = l >> 4, lr = l & 15;
    const int wm = wid >> 1, wn = wid & 1;
    const int dd = blockIdx.x;
    const int nt = (dd >> 3) & 7;
    const int mt = (dd & 7) + ((dd >> 6) << 3);
    const int m0 = mt * 128, n0 = nt * 64;
    const int arow = tid >> 1, ahalf = tid & 1;
    const float* aptr = x + (size_t)(m0 + arow) * 512 + ahalf * 32;

    f32x4 acc[4][6] = {};
    float4 xr[8];

    // ---- prologue: stage tile 0 into buf 0 ----
#pragma unroll
    for (int j = 0; j < 8; ++j) xr[j] = ((const float4*)aptr)[j];
#pragma unroll
    for (int i = 0; i < 6; ++i)
        gl2lds16(wtl + ((size_t)(nt * 8 + 0) * 3) * 8192 + i * 4096 + tid * 16,
                 &Bs[0][i * 4096 + tid * 16]);
#pragma unroll
    for (int jj = 0; jj < 4; ++jj) {
        u16x8 o;
        o[0] = f2bf(xr[2 * jj].x); o[1] = f2bf(xr[2 * jj].y);
        o[2] = f2bf(xr[2 * jj].z); o[3] = f2bf(xr[2 * jj].w);
        o[4] = f2bf(xr[2 * jj + 1].x); o[5] = f2bf(xr[2 * jj + 1].y);
        o[6] = f2bf(xr[2 * jj + 1].z); o[7] = f2bf(xr[2 * jj + 1].w);
        *(u16x8*)(&As[0][arow * 128 + (((ahalf * 4 + jj) ^ (arow & 7)) << 4)]) = o;
    }
    __syncthreads();

    // ---- main loop: one barrier per K-step ----
    for (int ks = 0; ks < 8; ++ks) {
        const int buf = ks & 1;
        if (ks < 7) {
            const float* ap = aptr + (ks + 1) * 64;
#pragma unroll
            for (int j = 0; j < 8; ++j) xr[j] = ((const float4*)ap)[j];
#pragma unroll
            for (int i = 0; i < 6; ++i)
                gl2lds16(wtl + ((size_t)((nt * 8 + ks + 1) * 3)) * 8192 + i * 4096 + tid * 16,
                         &Bs[buf ^ 1][i * 4096 + tid * 16]);
        }
        const unsigned char* Ab = &As[buf][0];
        const unsigned char* Bb = &Bs[buf][0];
        bf16x8 af[4][2];
#pragma unroll
        for (int mf = 0; mf < 4; ++mf) {
            int row = wm * 64 + mf * 16 + lr;
#pragma unroll
            for (int k2 = 0; k2 < 2; ++k2)
                af[mf][k2] = *(const bf16x8*)(Ab + row * 128 + (((k2 * 4 + g) ^ (row & 7)) << 4));
        }
#pragma unroll
        for (int k2 = 0; k2 < 2; ++k2) {
#pragma unroll
            for (int nf = 0; nf < 6; ++nf) {
                int f = wn * 6 + nf, mat = f >> 2, sub = f & 3;
                int brow = sub * 16 + lr;
                bf16x8 bv = *(const bf16x8*)(Bb + mat * 8192 + brow * 128 +
                                             (((k2 * 4 + g) ^ (brow & 7)) << 4));
#pragma unroll
                for (int mf = 0; mf < 4; ++mf)
                    acc[mf][nf] = MFMA16(af[mf][k2], bv, acc[mf][nf]);
            }
        }
        if (ks < 7) {
#pragma unroll
            for (int jj = 0; jj < 4; ++jj) {
                u16x8 o;
                o[0] = f2bf(xr[2 * jj].x); o[1] = f2bf(xr[2 * jj].y);
                o[2] = f2bf(xr[2 * jj].z); o[3] = f2bf(xr[2 * jj].w);
                o[4] = f2bf(xr[2 * jj + 1].x); o[5] = f2bf(xr[2 * jj + 1].y);
                o[6] = f2bf(xr[2 * jj + 1].z); o[7] = f2bf(xr[2 * jj + 1].w);
                *(u16x8*)(&As[buf ^ 1][arow * 128 + (((ahalf * 4 + jj) ^ (arow & 7)) << 4)]) = o;
            }
        }
        __syncthreads();
    }

    // ---- epilogue: stage acc into LDS tiles ----
    unsigned char* Eq = &As[0][0];           // [128 tok][64 d] swizzled
    unsigned char* Ek = &As[1][0];           // [128 tok][64 d] swizzled
    unsigned char* Ev = &Bs[0][0];           // [64 d][128 tok] swizzled
#pragma unroll
    for (int mf = 0; mf < 4; ++mf) {
#pragma unroll
        for (int nf = 0; nf < 6; ++nf) {
            int f = wn * 6 + nf, mat = f >> 2, sub = f & 3;
            int d5 = sub * 16 + lr;
#pragma unroll
            for (int r = 0; r < 4; ++r) {
                int tok = wm * 64 + mf * 16 + g * 4 + r;
                unsigned short v = f2bf(acc[mf][nf][r]);
                if (mat == 2) {
                    *(unsigned short*)(Ev + d5 * 256 + ((tok * 2) ^ ((d5 & 7) << 4))) = v;
                } else {
                    unsigned char* E = (mat == 0) ? Eq : Ek;
                    *(unsigned short*)(E + tok * 128 + (((d5 >> 3) ^ (tok & 7)) << 4) + (d5 & 7) * 2) = v;
                }
            }
        }
    }
    __syncthreads();

    const int b = m0 >> 14;
    const int nloc0 = m0 & 16383;
    if (wn == 1) {
        // ---- coalesced K and V store-out (waves 1,3) ----
        const int u = (wm << 6) | l;     // 0..127
#pragma unroll
        for (int pass = 0; pass < 8; ++pass) {
            int tok = pass * 16 + (u >> 3), j = u & 7;
            u16x8 v = *(const u16x8*)(Ek + tok * 128 + ((j ^ (tok & 7)) << 4));
            *(u16x8*)(Kbf + (size_t)(m0 + tok) * 512 + n0 + j * 8) = v;
        }
#pragma unroll
        for (int pass = 0; pass < 8; ++pass) {
            int d5 = pass * 8 + (u >> 4), j = u & 15;
            u16x8 v = *(const u16x8*)(Ev + d5 * 256 + ((j * 16) ^ ((d5 & 7) << 4)));
            *(u16x8*)(Vt + ((size_t)(b * 512 + n0 + d5)) * 16384 + nloc0 + j * 8) = v;
        }
    } else {
        // ---- fused q->agent softmax (waves 0,2); head h = nt ----
        const int h = nt;
        bf16x8 bq[2][2];
#pragma unroll
        for (int nfa = 0; nfa < 2; ++nfa)
#pragma unroll
            for (int kh = 0; kh < 2; ++kh)
                bq[nfa][kh] = *(const bf16x8*)(abf + (size_t)h * 2048 +
                                               (nfa * 16 + lr) * 64 + kh * 32 + g * 8);
        f32x4 p[4][2] = {};
#pragma unroll
        for (int mf = 0; mf < 4; ++mf) {
            int tok = wm * 64 + mf * 16 + lr;
#pragma unroll
            for (int kh = 0; kh < 2; ++kh) {
                bf16x8 aq = *(const bf16x8*)(Eq + tok * 128 + (((kh * 4 + g) ^ (tok & 7)) << 4));
                p[mf][0] = MFMA16(aq, bq[0][kh], p[mf][0]);
                p[mf][1] = MFMA16(aq, bq[1][kh], p[mf][1]);
            }
        }
        const size_t qbase = ((size_t)(mt * 4 + (h >> 1))) * 16384;
        const int c80 = (h & 1) * 4 + (lr >> 3);
#pragma unroll
        for (int mf = 0; mf < 4; ++mf) {
#pragma unroll
            for (int r = 0; r < 4; ++r) {
                float v0 = p[mf][0][r] * 0.125f, v1 = p[mf][1][r] * 0.125f;
                float m = fmaxf(v0, v1);
                m = fmaxf(m, __shfl_xor(m, 1));
                m = fmaxf(m, __shfl_xor(m, 2));
                m = fmaxf(m, __shfl_xor(m, 4));
                m = fmaxf(m, __shfl_xor(m, 8));
                float e0 = __expf(v0 - m), e1 = __expf(v1 - m);
                float s = e0 + e1;
                s += __shfl_xor(s, 1);
                s += __shfl_xor(s, 2);
                s += __shfl_xor(s, 4);
                s += __shfl_xor(s, 8);
                float inv = 1.0f / s;
                int row = wm * 64 + mf * 16 + g * 4 + r;
                size_t rb = qbase + row * 128 + (lr & 7) * 2;
                *(unsigned short*)(Qat + rb + ((c80 ^ (row & 7)) << 4)) = f2bf(e0 * inv);
                *(unsigned short*)(Qat + rb + (((c80 + 2) ^ (row & 7)) << 4)) = f2bf(e1 * inv);
            }
        }
    }
}

// ------------------------------- k_agent_part --------------------------------
// grid (64 chunks, 32 bh), block 256 (4 waves x 64 tokens).
__global__ __launch_bounds__(256) void k_agent_part(const unsigned short* __restrict__ Kbf,
                                                    const unsigned short* __restrict__ Vt,
                                                    const unsigned short* __restrict__ abf,
                                                    const int* __restrict__ mask,
                                                    float* __restrict__ part_pv,
                                                    float* __restrict__ part_ml) {
    __shared__ __align__(16) unsigned char Psm[4][2048];
    __shared__ float avs[4][2048];
    __shared__ float redM[4][32];
    __shared__ float redL[4][32];
    const int tid = threadIdx.x, l = tid & 63, wid = tid >> 6;
    const int g = l >> 4, lr = l & 15;
    const int c = blockIdx.x, bh = blockIdx.y, b = bh >> 3, h = bh & 7;
    const int tok0 = c * 256 + wid * 64;

    bf16x8 af[2][2];
#pragma unroll
    for (int mf = 0; mf < 2; ++mf)
#pragma unroll
        for (int ks = 0; ks < 2; ++ks)
            af[mf][ks] = *(const bf16x8*)(abf + (size_t)h * 2048 + (mf * 16 + lr) * 64 + ks * 32 + g * 8);

    const size_t kbase = (size_t)(b * 16384) * 512 + h * 64;
    const int maskbase = b * 16384;

    f32x4 sc[4][2];
#pragma unroll
    for (int it = 0; it < 4; ++it) {
        int tokn = tok0 + it * 16 + lr;
        const unsigned short* kp = Kbf + kbase + (size_t)tokn * 512;
        bf16x8 b0 = *(const bf16x8*)(kp + g * 8);
        bf16x8 b1 = *(const bf16x8*)(kp + 32 + g * 8);
        int mv = mask[maskbase + tokn];
        f32x4 z = {0.f, 0.f, 0.f, 0.f};
        f32x4 a0 = MFMA16(af[0][0], b0, z); a0 = MFMA16(af[0][1], b1, a0);
        f32x4 a1 = MFMA16(af[1][0], b0, z); a1 = MFMA16(af[1][1], b1, a1);
#pragma unroll
        for (int r = 0; r < 4; ++r) {
            a0[r] = (mv > 0) ? a0[r] * 0.125f : -1.0e9f;
            a1[r] = (mv > 0) ? a1[r] * 0.125f : -1.0e9f;
        }
        sc[it][0] = a0; sc[it][1] = a1;
    }

    float mx[8];
#pragma unroll
    for (int s = 0; s < 8; ++s) {
        float m = sc[0][s >> 2][s & 3];
        m = fmaxf(m, sc[1][s >> 2][s & 3]);
        m = fmaxf(m, sc[2][s >> 2][s & 3]);
        m = fmaxf(m, sc[3][s >> 2][s & 3]);
#pragma unroll
        for (int k = 1; k < 16; k <<= 1) m = fmaxf(m, __shfl_xor(m, k));
        mx[s] = m;
    }
    if (lr == 0) {
#pragma unroll
        for (int s = 0; s < 8; ++s) {
            int ag = (s >> 2) * 16 + g * 4 + (s & 3);
            redM[wid][ag] = mx[s];
        }
    }
    __syncthreads();
    float M[8];
#pragma unroll
    for (int s = 0; s < 8; ++s) {
        int ag = (s >> 2) * 16 + g * 4 + (s & 3);
        M[s] = fmaxf(fmaxf(redM[0][ag], redM[1][ag]), fmaxf(redM[2][ag], redM[3][ag]));
    }

    float le[8] = {0.f, 0.f, 0.f, 0.f, 0.f, 0.f, 0.f, 0.f};
    f32x4 pv[2][4] = {};
    unsigned char* Pw = &Psm[wid][0];
    const size_t vbase = ((size_t)b * 512 + h * 64) * 16384;
#pragma unroll
    for (int it2 = 0; it2 < 2; ++it2) {
#pragma unroll
        for (int half = 0; half < 2; ++half) {
            int it = it2 * 2 + half;
            int tk = half * 16 + lr;
#pragma unroll
            for (int s = 0; s < 8; ++s) {
                float p = __expf(sc[it][s >> 2][s & 3] - M[s]);
                le[s] += p;
                int ag = (s >> 2) * 16 + g * 4 + (s & 3);
                *(unsigned short*)(Pw + ag * 64 + ((2 * tk) ^ (((ag >> 2) & 3) << 4))) = f2bf(p);
            }
        }
        int n0w = tok0 + it2 * 32;
        bf16x8 pa[2];
#pragma unroll
        for (int mf = 0; mf < 2; ++mf) {
            int ag = mf * 16 + lr;
            pa[mf] = *(const bf16x8*)(Pw + ag * 64 + ((g * 16) ^ (((ag >> 2) & 3) << 4)));
        }
#pragma unroll
        for (int nf = 0; nf < 4; ++nf) {
            int dd = nf * 16 + lr;
            bf16x8 bv = *(const bf16x8*)(Vt + vbase + (size_t)dd * 16384 + n0w + g * 8);
#pragma unroll
            for (int mf = 0; mf < 2; ++mf)
                pv[mf][nf] = MFMA16(pa[mf], bv, pv[mf][nf]);
        }
    }

#pragma unroll
    for (int s = 0; s < 8; ++s) {
#pragma unroll
        for (int k = 1; k < 16; k <<= 1) le[s] += __shfl_xor(le[s], k);
    }
    if (lr == 0) {
#pragma unroll
        for (int s = 0; s < 8; ++s) {
            int ag = (s >> 2) * 16 + g * 4 + (s & 3);
            redL[wid][ag] = le[s];
        }
    }

#pragma unroll
    for (int mf = 0; mf < 2; ++mf)
#pragma unroll
        for (int nf = 0; nf < 4; ++nf)
#pragma unroll
            for (int r = 0; r < 4; ++r) {
                int ag = mf * 16 + g * 4 + r;
                int dd = nf * 16 + lr;
                avs[wid][ag * 64 + dd] = pv[mf][nf][r];
            }
    __syncthreads();

    float* pout = part_pv + ((size_t)bh * 64 + c) * 2048;
#pragma unroll
    for (int j = 0; j < 8; ++j) {
        int idx = tid + 256 * j;
        pout[idx] = avs[0][idx] + avs[1][idx] + avs[2][idx] + avs[3][idx];
    }
    if (wid == 0 && lr == 0) {
#pragma unroll
        for (int s = 0; s < 8; ++s) {
            int ag = (s >> 2) * 16 + g * 4 + (s & 3);
            float L = redL[0][ag] + redL[1][ag] + redL[2][ag] + redL[3][ag];
            size_t o = ((size_t)bh * 64 + c) * 64 + ag * 2;
            part_ml[o] = M[s];
            part_ml[o + 1] = L;
        }
    }
}

// ------------------------------- k_agent_comb --------------------------------
__global__ __launch_bounds__(256) void k_agent_comb(const float* __restrict__ part_pv,
                                                    const float* __restrict__ part_ml,
                                                    unsigned short* __restrict__ avbf) {
    __shared__ float scl[64][4];
    __shared__ float iLg[4], Mg[4];
    const int tid = threadIdx.x;
    const int ag0 = blockIdx.x * 4, bh = blockIdx.y;
    if (tid < 4) {
        int ag = ag0 + tid;
        const float* ml = part_ml + (size_t)bh * 4096 + ag * 2;
        float M = -3.0e38f;
#pragma unroll 4
        for (int c = 0; c < 64; ++c) M = fmaxf(M, ml[c * 64]);
        float L = 0.f;
#pragma unroll 4
        for (int c = 0; c < 64; ++c) L += __expf(ml[c * 64] - M) * ml[c * 64 + 1];
        Mg[tid] = M; iLg[tid] = 1.0f / L;
    }
    __syncthreads();
    {
        int c = tid >> 2, agl = tid & 3;
        scl[c][agl] = __expf(part_ml[(size_t)bh * 4096 + (size_t)c * 64 + (ag0 + agl) * 2] - Mg[agl]);
    }
    __syncthreads();
    const int agl = tid >> 6, dd = tid & 63;
    const float* pv = part_pv + (size_t)bh * 64 * 2048 + (size_t)(ag0 + agl) * 64 + dd;
    float acc = 0.f;
#pragma unroll 4
    for (int c = 0; c < 64; ++c) acc += scl[c][agl] * pv[(size_t)c * 2048];
    avbf[(size_t)bh * 2048 + (size_t)(ag0 + agl) * 64 + dd] = f2bf(acc * iLg[agl]);
}

// ------------------------------- k_avp ----------------------------------------
// AVP tiled write: tile ((b*4+jt)*4+kst) of [128 j][64 k] swizzled.
__global__ __launch_bounds__(64) void k_avp(const unsigned short* __restrict__ avbf,
                                            const unsigned short* __restrict__ Wpt,
                                            unsigned char* __restrict__ AVPt) {
    const int l = threadIdx.x & 63;
    const int bh = blockIdx.x, b = bh >> 3, h = bh & 7;
    const int g = l >> 4, lr = l & 15;
    bf16x8 avf[2][2];
#pragma unroll
    for (int mf = 0; mf < 2; ++mf)
#pragma unroll
        for (int ks = 0; ks < 2; ++ks)
            avf[mf][ks] = *(const bf16x8*)(avbf + (size_t)bh * 2048 + (mf * 16 + lr) * 64 + ks * 32 + g * 8);
    const int kst = h >> 1;
#pragma unroll 4
    for (int nf = 0; nf < 32; ++nf) {
        int j = nf * 16 + lr;
        bf16x8 w0 = *(const bf16x8*)(Wpt + (size_t)j * 512 + h * 64 + g * 8);
        bf16x8 w1 = *(const bf16x8*)(Wpt + (size_t)j * 512 + h * 64 + 32 + g * 8);
        int jt = j >> 7, row = j & 127;
#pragma unroll
        for (int mf = 0; mf < 2; ++mf) {
            f32x4 z = {0.f, 0.f, 0.f, 0.f};
            f32x4 acc = MFMA16(avf[mf][0], w0, z);
            acc = MFMA16(avf[mf][1], w1, acc);
            u16x4 o;
            o[0] = f2bf(acc[0]); o[1] = f2bf(acc[1]); o[2] = f2bf(acc[2]); o[3] = f2bf(acc[3]);
            int c8 = (h & 1) * 4 + mf * 2 + (g >> 1);
            size_t byte = ((size_t)((b * 4 + jt) * 4 + kst)) * 16384 + row * 128 +
                          ((c8 ^ (row & 7)) << 4) + (g & 1) * 8;
            *(u16x4*)(AVPt + byte) = o;
        }
    }
}

// ------------------------------- k_out -----------------------------------------
// BM=128, BN=128, BK=64, K=256; gload_lds staging of tiled Qattn/AVPt.
__global__ __launch_bounds__(256) void k_out(const unsigned char* __restrict__ Qat,
                                             const unsigned char* __restrict__ AVPt,
                                             const int* __restrict__ mask,
                                             float* __restrict__ out) {
    __shared__ __align__(16) unsigned char As[16384];
    __shared__ __align__(16) unsigned char Bs[16384];
    const int tid = threadIdx.x, l = tid & 63, wid = tid >> 6;
    const int wm = wid >> 1, wn = wid & 1;
    const int g = l >> 4, lr = l & 15;
    const int d = blockIdx.x;
    const int nt = (d >> 3) & 3;
    const int mt = (d & 7) + ((d >> 5) << 3);
    const int m0 = mt * 128, j0 = nt * 128;
    const int b = m0 >> 14;
    f32x4 acc[4][4] = {};

    for (int ks = 0; ks < 4; ++ks) {
        const size_t abase = ((size_t)(mt * 4 + ks)) * 16384;
        const size_t bbase = ((size_t)((b * 4 + nt) * 4 + ks)) * 16384;
#pragma unroll
        for (int i = 0; i < 4; ++i) {
            gl2lds16(Qat + abase + i * 4096 + tid * 16, As + i * 4096 + tid * 16);
            gl2lds16(AVPt + bbase + i * 4096 + tid * 16, Bs + i * 4096 + tid * 16);
        }
        __syncthreads();
        bf16x8 af[4][2];
#pragma unroll
        for (int mf = 0; mf < 4; ++mf) {
            int row = wm * 64 + mf * 16 + lr;
#pragma unroll
            for (int k2 = 0; k2 < 2; ++k2)
                af[mf][k2] = *(const bf16x8*)(As + row * 128 + (((k2 * 4 + g) ^ (row & 7)) << 4));
        }
#pragma unroll
        for (int k2 = 0; k2 < 2; ++k2) {
#pragma unroll
            for (int nf = 0; nf < 4; ++nf) {
                int brow = wn * 64 + nf * 16 + lr;
                bf16x8 bv = *(const bf16x8*)(Bs + brow * 128 + (((k2 * 4 + g) ^ (brow & 7)) << 4));
#pragma unroll
                for (int mf = 0; mf < 4; ++mf)
                    acc[mf][nf] = MFMA16(af[mf][k2], bv, acc[mf][nf]);
            }
        }
        __syncthreads();
    }
#pragma unroll
    for (int mf = 0; mf < 4; ++mf) {
        int trow = m0 + wm * 64 + mf * 16 + g * 4;
#pragma unroll
        for (int r = 0; r < 4; ++r) {
            float mv = (mask[trow + r] > 0) ? 1.0f : 0.0f;
#pragma unroll
            for (int nf = 0; nf < 4; ++nf) {
                int j = j0 + wn * 64 + nf * 16 + lr;
                out[(size_t)(trow + r) * 512 + j] = acc[mf][nf][r] * mv;
            }
        }
    }
}

// ------------------------------- launch -----------------------------------------
extern "C" void kernel_launch(void* const* d_in, const int* in_sizes, int n_in,
                              void* d_out, int out_size, void* d_ws, size_t ws_size,
                              hipStream_t stream) {
    const float* x  = (const float*)d_in[0];
    const int*  mk  = (const int*)d_in[1];
    const float* at = (const float*)d_in[2];
    const float* Wq = (const float*)d_in[3];
    const float* Wk = (const float*)d_in[4];
    const float* Wv = (const float*)d_in[5];
    const float* Wp = (const float*)d_in[6];
    float* out = (float*)d_out;
    char* ws = (char*)d_ws;

    unsigned char*  Qat   = (unsigned char*)(ws);                        // [0,32) MiB tiled
    float* part_pv = (float*)(ws + ((size_t)32 << 20));                  // [32,48.8) MiB
    float* part_ml = (float*)(ws + ((size_t)52 << 20));                  // [52,52.5) MiB
    unsigned short* Kbf   = (unsigned short*)(ws + ((size_t)64 << 20));  // [64,128)
    unsigned short* Vt    = (unsigned short*)(ws + ((size_t)128 << 20)); // [128,192)
    unsigned short* Wt    = (unsigned short*)(ws + ((size_t)256 << 20)); // [256,258) row-major
    unsigned char*  wtl   = (unsigned char*)(ws + ((size_t)258 << 20));  // [258,259.5) tiled QKV weights
    unsigned short* abf   = (unsigned short*)(ws + ((size_t)259 << 20) + (512 << 10)); // 259.5 MiB, 32 KiB
    unsigned short* avbf  = (unsigned short*)(ws + ((size_t)259 << 20) + (576 << 10)); // +128 KiB
    unsigned char*  AVPt  = (unsigned char*)(ws + ((size_t)260 << 20));  // [260,261) tiled

    k_w_t<<<dim3(16, 16, 4), 256, 0, stream>>>(Wq, Wk, Wv, Wp, Wt);
    k_w_tile<<<dim3(8, 8, 3), 256, 0, stream>>>(Wq, Wk, Wv, wtl);
    k_pack_a<<<64, 256, 0, stream>>>(at, abf);
    k_qkv<<<4096, 256, 0, stream>>>(x, wtl, abf, Qat, Kbf, Vt);
    k_agent_part<<<dim3(64, 32), 256, 0, stream>>>(Kbf, Vt, abf, mk, part_pv, part_ml);
    k_agent_comb<<<dim3(8, 32), 256, 0, stream>>>(part_pv, part_ml, avbf);
    k_avp<<<32, 64, 0, stream>>>(avbf, Wt + 786432, AVPt);
    k_out<<<2048, 256, 0, stream>>>(Qat, AVPt, mk, out);
}

// Round 6
// 309.837 us; speedup vs baseline: 1.7931x; 1.7931x over previous
//
#include <hip/hip_runtime.h>

// ---------------------------------------------------------------------------
// MaskedSuperAttention (agent attention), B=4 N=16384 C=512 H=8 HD=64 NA=32
//   k_cvt_x      : x f32 -> xt bf16, TILED (128x64 tiles, XOR-swizzled rows)
//   k_w_t_p      : Wproj f32 [k][n] -> Wpt bf16 [n][k] row-major (for k_avp)
//   k_w_tile     : Wq/Wk/Wv -> wtl tiled-swizzled (for k_qkv gload_lds)
//   k_pack_a     : agent_tokens -> abf [h][32][64] bf16
//   k_qkv        : R4 main loop (single-buffer gl2lds, 40KB LDS) ; epilogue
//                  stores K (row), V (transposed) and computes q->agent
//                  softmax in-kernel -> Qattn TILED (Q never touches HBM)
//   k_agent_part : split-K flash partials ; grid 2048
//   k_agent_comb : merge partials -> agent_v bf16
//   k_avp        : AVP = agent_v @ Wproj -> AVPt TILED
//   k_out        : out = (Qattn @ AVPt) * keymask ; gload_lds staging
// Tiled layout: tile = 128 rows x 64 k (16 KiB); byte(row,c8) =
//   base + row*128 + ((c8 ^ (row&7))<<4)   (c8 = 16B slot, 0..7)
// R6: R5's dbuf+reg-staged k_qkv regressed 3x (80KB LDS -> 2 blocks/CU,
// occupancy 11%, latency-bound). Reverted to R4 loop; kept only the
// (correctness-proven) fused q-attn epilogue.
// ---------------------------------------------------------------------------

typedef float  f32x4   __attribute__((ext_vector_type(4)));
typedef short  bf16x8  __attribute__((ext_vector_type(8)));
typedef unsigned short u16x4 __attribute__((ext_vector_type(4)));
typedef unsigned short u16x8 __attribute__((ext_vector_type(8)));

#define MFMA16(a, b, c) __builtin_amdgcn_mfma_f32_16x16x32_bf16((a), (b), (c), 0, 0, 0)

__device__ __forceinline__ unsigned short f2bf(float f) {
    unsigned u = __builtin_bit_cast(unsigned, f);
    u += 0x7FFFu + ((u >> 16) & 1u);        // RTNE
    return (unsigned short)(u >> 16);
}
__device__ __forceinline__ float bf2f(unsigned short h) {
    unsigned u = ((unsigned)h) << 16;
    return __builtin_bit_cast(float, u);
}
__device__ __forceinline__ void gl2lds16(const void* g, void* l) {
    __builtin_amdgcn_global_load_lds(
        (const __attribute__((address_space(1))) unsigned int*)g,
        (__attribute__((address_space(3))) unsigned int*)l, 16, 0, 0);
}

// ------------------------------- k_cvt_x -----------------------------------
// x f32 [tok][512] -> xt tiled: tile t = mt*8+ks, 16 KiB each, swizzled.
__global__ __launch_bounds__(256) void k_cvt_x(const float* __restrict__ x,
                                               unsigned char* __restrict__ xt) {
    int v = blockIdx.x * 256 + threadIdx.x;
    int tile = v >> 10;             // 0..4095
    int q = v & 1023;
    int row = q >> 3, c = q & 7;
    int mt = tile >> 3, ks = tile & 7;
    const float* sp = x + ((size_t)(mt * 128 + row)) * 512 + ks * 64 + c * 8;
    float4 v0 = *(const float4*)sp;
    float4 v1 = *(const float4*)(sp + 4);
    u16x8 o;
    o[0] = f2bf(v0.x); o[1] = f2bf(v0.y); o[2] = f2bf(v0.z); o[3] = f2bf(v0.w);
    o[4] = f2bf(v1.x); o[5] = f2bf(v1.y); o[6] = f2bf(v1.z); o[7] = f2bf(v1.w);
    *(u16x8*)(xt + (size_t)tile * 16384 + row * 128 + ((c ^ (row & 7)) << 4)) = o;
}

// ------------------------------- k_w_t_p ------------------------------------
// Wproj only: f32 [k][n] -> Wpt bf16 [n][k]. grid (16,16), block 256.
__global__ __launch_bounds__(256) void k_w_t_p(const float* __restrict__ Wp,
                                               unsigned short* __restrict__ Wpt) {
    __shared__ float t[32][33];
    const int k0 = blockIdx.y * 32, n0 = blockIdx.x * 32;
#pragma unroll
    for (int j = 0; j < 4; ++j) {
        int i = threadIdx.x + 256 * j;
        int ky = i >> 5, nx = i & 31;
        t[ky][nx] = Wp[(size_t)(k0 + ky) * 512 + n0 + nx];
    }
    __syncthreads();
#pragma unroll
    for (int j = 0; j < 4; ++j) {
        int i = threadIdx.x + 256 * j;
        int ny = i >> 5, kx = i & 31;
        Wpt[(size_t)(n0 + ny) * 512 + k0 + kx] = f2bf(t[kx][ny]);
    }
}

// ------------------------------- k_w_tile -----------------------------------
// Wq/Wk/Wv -> tiled-swizzled wtl: trio tile (nt,ks,mat) of [64 n][64 k], 8 KiB.
__global__ __launch_bounds__(256) void k_w_tile(const float* __restrict__ Wq,
                                                const float* __restrict__ Wk,
                                                const float* __restrict__ Wv,
                                                unsigned char* __restrict__ wtl) {
    const int ks = blockIdx.x, nt = blockIdx.y, mat = blockIdx.z;
    const float* src = (mat == 0) ? Wq : (mat == 1) ? Wk : Wv;
    const size_t dbase = ((size_t)((nt * 8 + ks) * 3 + mat)) * 8192;
    const int row = threadIdx.x & 63;
#pragma unroll
    for (int cc = 0; cc < 2; ++cc) {
        int c = (threadIdx.x >> 6) + cc * 4;
        u16x8 o;
#pragma unroll
        for (int j = 0; j < 8; ++j)
            o[j] = f2bf(src[(size_t)(ks * 64 + c * 8 + j) * 512 + nt * 64 + row]);
        *(u16x8*)(wtl + dbase + row * 128 + ((c ^ (row & 7)) << 4)) = o;
    }
}

// ------------------------------- k_pack_a -----------------------------------
__global__ __launch_bounds__(256) void k_pack_a(const float* __restrict__ at,
                                                unsigned short* __restrict__ abf) {
    int idx = threadIdx.x + blockIdx.x * 256;       // 0..16383
    int h = idx >> 11, ag = (idx >> 6) & 31, d = idx & 63;
    abf[idx] = f2bf(at[ag * 512 + h * 64 + d]);
}

// ------------------------------- k_qkv ---------------------------------------
// BM=128, BN=192 (Q64,K64,V64), BK=64. 4 waves 2x2, wave tile 64x96.
// grid 4096 (XCD-swizzled), block 256. gload_lds staging of pre-swizzled tiles.
// Epilogue: K,V direct stores; Q -> LDS -> fused q-attn softmax -> Qat tiled.
__global__ __launch_bounds__(256) void k_qkv(const unsigned char* __restrict__ xt,
                                             const unsigned char* __restrict__ wtl,
                                             const unsigned short* __restrict__ abf,
                                             unsigned char* __restrict__ Qat,
                                             unsigned short* __restrict__ Kbf,
                                             unsigned short* __restrict__ Vt) {
    __shared__ __align__(16) unsigned char As[16384];
    __shared__ __align__(16) unsigned char Bs[24576];
    const int tid = threadIdx.x, l = tid & 63, wid = tid >> 6;
    const int g = l >> 4, lr = l & 15;
    const int wm = wid >> 1, wn = wid & 1;
    const int dd = blockIdx.x;
    const int nt = (dd >> 3) & 7;
    const int mt = (dd & 7) + ((dd >> 6) << 3);
    const int m0 = mt * 128, n0 = nt * 64;

    f32x4 acc[4][6] = {};

    for (int ks = 0; ks < 8; ++ks) {
        const size_t abase = ((size_t)(mt * 8 + ks)) * 16384;
        const size_t bbase = ((size_t)((nt * 8 + ks) * 3)) * 8192;
#pragma unroll
        for (int i = 0; i < 4; ++i)
            gl2lds16(xt + abase + i * 4096 + tid * 16, As + i * 4096 + tid * 16);
#pragma unroll
        for (int i = 0; i < 6; ++i)
            gl2lds16(wtl + bbase + i * 4096 + tid * 16, Bs + i * 4096 + tid * 16);
        __syncthreads();

        bf16x8 af[4][2];
#pragma unroll
        for (int mf = 0; mf < 4; ++mf) {
            int row = wm * 64 + mf * 16 + lr;
#pragma unroll
            for (int k2 = 0; k2 < 2; ++k2)
                af[mf][k2] = *(const bf16x8*)(As + row * 128 + (((k2 * 4 + g) ^ (row & 7)) << 4));
        }
#pragma unroll
        for (int k2 = 0; k2 < 2; ++k2) {
#pragma unroll
            for (int nf = 0; nf < 6; ++nf) {
                int f = wn * 6 + nf, mat = f >> 2, sub = f & 3;
                int brow = sub * 16 + lr;
                bf16x8 bv = *(const bf16x8*)(Bs + mat * 8192 + brow * 128 +
                                             (((k2 * 4 + g) ^ (brow & 7)) << 4));
#pragma unroll
                for (int mf = 0; mf < 4; ++mf)
                    acc[mf][nf] = MFMA16(af[mf][k2], bv, acc[mf][nf]);
            }
        }
        __syncthreads();
    }

    // ---- epilogue: K,V direct; Q staged to LDS (reuse As) for fused q-attn ----
    const int b = m0 >> 14;
    const int nloc0 = m0 & 16383;
    unsigned char* Eq = As;                      // [128 tok][64 d] swizzled, 16 KiB
#pragma unroll
    for (int mf = 0; mf < 4; ++mf) {
#pragma unroll
        for (int nf = 0; nf < 6; ++nf) {
            int f = wn * 6 + nf, mat = f >> 2, sub = f & 3;
            int dc = n0 + sub * 16 + lr;
            if (mat == 0) {
                int d5 = sub * 16 + lr;
#pragma unroll
                for (int r = 0; r < 4; ++r) {
                    int tok = wm * 64 + mf * 16 + g * 4 + r;
                    *(unsigned short*)(Eq + tok * 128 + (((d5 >> 3) ^ (tok & 7)) << 4) +
                                       (d5 & 7) * 2) = f2bf(acc[mf][nf][r]);
                }
            } else if (mat == 1) {
                int trow = wm * 64 + mf * 16 + g * 4;
#pragma unroll
                for (int r = 0; r < 4; ++r)
                    Kbf[(size_t)(m0 + trow + r) * 512 + dc] = f2bf(acc[mf][nf][r]);
            } else {
                int trow = wm * 64 + mf * 16 + g * 4;
                u16x4 vv;
                vv[0] = f2bf(acc[mf][nf][0]); vv[1] = f2bf(acc[mf][nf][1]);
                vv[2] = f2bf(acc[mf][nf][2]); vv[3] = f2bf(acc[mf][nf][3]);
                *(u16x4*)(Vt + ((size_t)(b * 512 + dc)) * 16384 + nloc0 + trow) = vv;
            }
        }
    }
    __syncthreads();

    if (wn == 0) {
        // ---- fused q->agent softmax (waves 0,2); head h = nt ----
        const int h = nt;
        bf16x8 bq[2][2];
#pragma unroll
        for (int nfa = 0; nfa < 2; ++nfa)
#pragma unroll
            for (int kh = 0; kh < 2; ++kh)
                bq[nfa][kh] = *(const bf16x8*)(abf + (size_t)h * 2048 +
                                               (nfa * 16 + lr) * 64 + kh * 32 + g * 8);
        f32x4 p[4][2] = {};
#pragma unroll
        for (int mf = 0; mf < 4; ++mf) {
            int tok = wm * 64 + mf * 16 + lr;
#pragma unroll
            for (int kh = 0; kh < 2; ++kh) {
                bf16x8 aq = *(const bf16x8*)(Eq + tok * 128 + (((kh * 4 + g) ^ (tok & 7)) << 4));
                p[mf][0] = MFMA16(aq, bq[0][kh], p[mf][0]);
                p[mf][1] = MFMA16(aq, bq[1][kh], p[mf][1]);
            }
        }
        const size_t qbase = ((size_t)(mt * 4 + (h >> 1))) * 16384;
        const int c80 = (h & 1) * 4 + (lr >> 3);
#pragma unroll
        for (int mf = 0; mf < 4; ++mf) {
#pragma unroll
            for (int r = 0; r < 4; ++r) {
                float v0 = p[mf][0][r] * 0.125f, v1 = p[mf][1][r] * 0.125f;
                float m = fmaxf(v0, v1);
                m = fmaxf(m, __shfl_xor(m, 1));
                m = fmaxf(m, __shfl_xor(m, 2));
                m = fmaxf(m, __shfl_xor(m, 4));
                m = fmaxf(m, __shfl_xor(m, 8));
                float e0 = __expf(v0 - m), e1 = __expf(v1 - m);
                float s = e0 + e1;
                s += __shfl_xor(s, 1);
                s += __shfl_xor(s, 2);
                s += __shfl_xor(s, 4);
                s += __shfl_xor(s, 8);
                float inv = 1.0f / s;
                int row = wm * 64 + mf * 16 + g * 4 + r;
                size_t rb = qbase + row * 128 + (lr & 7) * 2;
                *(unsigned short*)(Qat + rb + ((c80 ^ (row & 7)) << 4)) = f2bf(e0 * inv);
                *(unsigned short*)(Qat + rb + (((c80 + 2) ^ (row & 7)) << 4)) = f2bf(e1 * inv);
            }
        }
    }
}

// ------------------------------- k_agent_part --------------------------------
// grid (64 chunks, 32 bh), block 256 (4 waves x 64 tokens).
__global__ __launch_bounds__(256) void k_agent_part(const unsigned short* __restrict__ Kbf,
                                                    const unsigned short* __restrict__ Vt,
                                                    const unsigned short* __restrict__ abf,
                                                    const int* __restrict__ mask,
                                                    float* __restrict__ part_pv,
                                                    float* __restrict__ part_ml) {
    __shared__ __align__(16) unsigned char Psm[4][2048];
    __shared__ float avs[4][2048];
    __shared__ float redM[4][32];
    __shared__ float redL[4][32];
    const int tid = threadIdx.x, l = tid & 63, wid = tid >> 6;
    const int g = l >> 4, lr = l & 15;
    const int c = blockIdx.x, bh = blockIdx.y, b = bh >> 3, h = bh & 7;
    const int tok0 = c * 256 + wid * 64;

    bf16x8 af[2][2];
#pragma unroll
    for (int mf = 0; mf < 2; ++mf)
#pragma unroll
        for (int ks = 0; ks < 2; ++ks)
            af[mf][ks] = *(const bf16x8*)(abf + (size_t)h * 2048 + (mf * 16 + lr) * 64 + ks * 32 + g * 8);

    const size_t kbase = (size_t)(b * 16384) * 512 + h * 64;
    const int maskbase = b * 16384;

    f32x4 sc[4][2];
#pragma unroll
    for (int it = 0; it < 4; ++it) {
        int tokn = tok0 + it * 16 + lr;
        const unsigned short* kp = Kbf + kbase + (size_t)tokn * 512;
        bf16x8 b0 = *(const bf16x8*)(kp + g * 8);
        bf16x8 b1 = *(const bf16x8*)(kp + 32 + g * 8);
        int mv = mask[maskbase + tokn];
        f32x4 z = {0.f, 0.f, 0.f, 0.f};
        f32x4 a0 = MFMA16(af[0][0], b0, z); a0 = MFMA16(af[0][1], b1, a0);
        f32x4 a1 = MFMA16(af[1][0], b0, z); a1 = MFMA16(af[1][1], b1, a1);
#pragma unroll
        for (int r = 0; r < 4; ++r) {
            a0[r] = (mv > 0) ? a0[r] * 0.125f : -1.0e9f;
            a1[r] = (mv > 0) ? a1[r] * 0.125f : -1.0e9f;
        }
        sc[it][0] = a0; sc[it][1] = a1;
    }

    float mx[8];
#pragma unroll
    for (int s = 0; s < 8; ++s) {
        float m = sc[0][s >> 2][s & 3];
        m = fmaxf(m, sc[1][s >> 2][s & 3]);
        m = fmaxf(m, sc[2][s >> 2][s & 3]);
        m = fmaxf(m, sc[3][s >> 2][s & 3]);
#pragma unroll
        for (int k = 1; k < 16; k <<= 1) m = fmaxf(m, __shfl_xor(m, k));
        mx[s] = m;
    }
    if (lr == 0) {
#pragma unroll
        for (int s = 0; s < 8; ++s) {
            int ag = (s >> 2) * 16 + g * 4 + (s & 3);
            redM[wid][ag] = mx[s];
        }
    }
    __syncthreads();
    float M[8];
#pragma unroll
    for (int s = 0; s < 8; ++s) {
        int ag = (s >> 2) * 16 + g * 4 + (s & 3);
        M[s] = fmaxf(fmaxf(redM[0][ag], redM[1][ag]), fmaxf(redM[2][ag], redM[3][ag]));
    }

    float le[8] = {0.f, 0.f, 0.f, 0.f, 0.f, 0.f, 0.f, 0.f};
    f32x4 pv[2][4] = {};
    unsigned char* Pw = &Psm[wid][0];
    const size_t vbase = ((size_t)b * 512 + h * 64) * 16384;
#pragma unroll
    for (int it2 = 0; it2 < 2; ++it2) {
#pragma unroll
        for (int half = 0; half < 2; ++half) {
            int it = it2 * 2 + half;
            int tk = half * 16 + lr;
#pragma unroll
            for (int s = 0; s < 8; ++s) {
                float p = __expf(sc[it][s >> 2][s & 3] - M[s]);
                le[s] += p;
                int ag = (s >> 2) * 16 + g * 4 + (s & 3);
                *(unsigned short*)(Pw + ag * 64 + ((2 * tk) ^ (((ag >> 2) & 3) << 4))) = f2bf(p);
            }
        }
        int n0w = tok0 + it2 * 32;
        bf16x8 pa[2];
#pragma unroll
        for (int mf = 0; mf < 2; ++mf) {
            int ag = mf * 16 + lr;
            pa[mf] = *(const bf16x8*)(Pw + ag * 64 + ((g * 16) ^ (((ag >> 2) & 3) << 4)));
        }
#pragma unroll
        for (int nf = 0; nf < 4; ++nf) {
            int dd = nf * 16 + lr;
            bf16x8 bv = *(const bf16x8*)(Vt + vbase + (size_t)dd * 16384 + n0w + g * 8);
#pragma unroll
            for (int mf = 0; mf < 2; ++mf)
                pv[mf][nf] = MFMA16(pa[mf], bv, pv[mf][nf]);
        }
    }

#pragma unroll
    for (int s = 0; s < 8; ++s) {
#pragma unroll
        for (int k = 1; k < 16; k <<= 1) le[s] += __shfl_xor(le[s], k);
    }
    if (lr == 0) {
#pragma unroll
        for (int s = 0; s < 8; ++s) {
            int ag = (s >> 2) * 16 + g * 4 + (s & 3);
            redL[wid][ag] = le[s];
        }
    }

#pragma unroll
    for (int mf = 0; mf < 2; ++mf)
#pragma unroll
        for (int nf = 0; nf < 4; ++nf)
#pragma unroll
            for (int r = 0; r < 4; ++r) {
                int ag = mf * 16 + g * 4 + r;
                int dd = nf * 16 + lr;
                avs[wid][ag * 64 + dd] = pv[mf][nf][r];
            }
    __syncthreads();

    float* pout = part_pv + ((size_t)bh * 64 + c) * 2048;
#pragma unroll
    for (int j = 0; j < 8; ++j) {
        int idx = tid + 256 * j;
        pout[idx] = avs[0][idx] + avs[1][idx] + avs[2][idx] + avs[3][idx];
    }
    if (wid == 0 && lr == 0) {
#pragma unroll
        for (int s = 0; s < 8; ++s) {
            int ag = (s >> 2) * 16 + g * 4 + (s & 3);
            float L = redL[0][ag] + redL[1][ag] + redL[2][ag] + redL[3][ag];
            size_t o = ((size_t)bh * 64 + c) * 64 + ag * 2;
            part_ml[o] = M[s];
            part_ml[o + 1] = L;
        }
    }
}

// ------------------------------- k_agent_comb --------------------------------
__global__ __launch_bounds__(256) void k_agent_comb(const float* __restrict__ part_pv,
                                                    const float* __restrict__ part_ml,
                                                    unsigned short* __restrict__ avbf) {
    __shared__ float scl[64][4];
    __shared__ float iLg[4], Mg[4];
    const int tid = threadIdx.x;
    const int ag0 = blockIdx.x * 4, bh = blockIdx.y;
    if (tid < 4) {
        int ag = ag0 + tid;
        const float* ml = part_ml + (size_t)bh * 4096 + ag * 2;
        float M = -3.0e38f;
#pragma unroll 4
        for (int c = 0; c < 64; ++c) M = fmaxf(M, ml[c * 64]);
        float L = 0.f;
#pragma unroll 4
        for (int c = 0; c < 64; ++c) L += __expf(ml[c * 64] - M) * ml[c * 64 + 1];
        Mg[tid] = M; iLg[tid] = 1.0f / L;
    }
    __syncthreads();
    {
        int c = tid >> 2, agl = tid & 3;
        scl[c][agl] = __expf(part_ml[(size_t)bh * 4096 + (size_t)c * 64 + (ag0 + agl) * 2] - Mg[agl]);
    }
    __syncthreads();
    const int agl = tid >> 6, dd = tid & 63;
    const float* pv = part_pv + (size_t)bh * 64 * 2048 + (size_t)(ag0 + agl) * 64 + dd;
    float acc = 0.f;
#pragma unroll 4
    for (int c = 0; c < 64; ++c) acc += scl[c][agl] * pv[(size_t)c * 2048];
    avbf[(size_t)bh * 2048 + (size_t)(ag0 + agl) * 64 + dd] = f2bf(acc * iLg[agl]);
}

// ------------------------------- k_avp ----------------------------------------
// AVP tiled write: tile ((b*4+jt)*4+kst) of [128 j][64 k] swizzled.
__global__ __launch_bounds__(64) void k_avp(const unsigned short* __restrict__ avbf,
                                            const unsigned short* __restrict__ Wpt,
                                            unsigned char* __restrict__ AVPt) {
    const int l = threadIdx.x & 63;
    const int bh = blockIdx.x, b = bh >> 3, h = bh & 7;
    const int g = l >> 4, lr = l & 15;
    bf16x8 avf[2][2];
#pragma unroll
    for (int mf = 0; mf < 2; ++mf)
#pragma unroll
        for (int ks = 0; ks < 2; ++ks)
            avf[mf][ks] = *(const bf16x8*)(avbf + (size_t)bh * 2048 + (mf * 16 + lr) * 64 + ks * 32 + g * 8);
    const int kst = h >> 1;
#pragma unroll 4
    for (int nf = 0; nf < 32; ++nf) {
        int j = nf * 16 + lr;
        bf16x8 w0 = *(const bf16x8*)(Wpt + (size_t)j * 512 + h * 64 + g * 8);
        bf16x8 w1 = *(const bf16x8*)(Wpt + (size_t)j * 512 + h * 64 + 32 + g * 8);
        int jt = j >> 7, row = j & 127;
#pragma unroll
        for (int mf = 0; mf < 2; ++mf) {
            f32x4 z = {0.f, 0.f, 0.f, 0.f};
            f32x4 acc = MFMA16(avf[mf][0], w0, z);
            acc = MFMA16(avf[mf][1], w1, acc);
            u16x4 o;
            o[0] = f2bf(acc[0]); o[1] = f2bf(acc[1]); o[2] = f2bf(acc[2]); o[3] = f2bf(acc[3]);
            int c8 = (h & 1) * 4 + mf * 2 + (g >> 1);
            size_t byte = ((size_t)((b * 4 + jt) * 4 + kst)) * 16384 + row * 128 +
                          ((c8 ^ (row & 7)) << 4) + (g & 1) * 8;
            *(u16x4*)(AVPt + byte) = o;
        }
    }
}

// ------------------------------- k_out -----------------------------------------
// BM=128, BN=128, BK=64, K=256; gload_lds staging of tiled Qattn/AVPt.
__global__ __launch_bounds__(256) void k_out(const unsigned char* __restrict__ Qat,
                                             const unsigned char* __restrict__ AVPt,
                                             const int* __restrict__ mask,
                                             float* __restrict__ out) {
    __shared__ __align__(16) unsigned char As[16384];
    __shared__ __align__(16) unsigned char Bs[16384];
    const int tid = threadIdx.x, l = tid & 63, wid = tid >> 6;
    const int wm = wid >> 1, wn = wid & 1;
    const int g = l >> 4, lr = l & 15;
    const int d = blockIdx.x;
    const int nt = (d >> 3) & 3;
    const int mt = (d & 7) + ((d >> 5) << 3);
    const int m0 = mt * 128, j0 = nt * 128;
    const int b = m0 >> 14;
    f32x4 acc[4][4] = {};

    for (int ks = 0; ks < 4; ++ks) {
        const size_t abase = ((size_t)(mt * 4 + ks)) * 16384;
        const size_t bbase = ((size_t)((b * 4 + nt) * 4 + ks)) * 16384;
#pragma unroll
        for (int i = 0; i < 4; ++i) {
            gl2lds16(Qat + abase + i * 4096 + tid * 16, As + i * 4096 + tid * 16);
            gl2lds16(AVPt + bbase + i * 4096 + tid * 16, Bs + i * 4096 + tid * 16);
        }
        __syncthreads();
        bf16x8 af[4][2];
#pragma unroll
        for (int mf = 0; mf < 4; ++mf) {
            int row = wm * 64 + mf * 16 + lr;
#pragma unroll
            for (int k2 = 0; k2 < 2; ++k2)
                af[mf][k2] = *(const bf16x8*)(As + row * 128 + (((k2 * 4 + g) ^ (row & 7)) << 4));
        }
#pragma unroll
        for (int k2 = 0; k2 < 2; ++k2) {
#pragma unroll
            for (int nf = 0; nf < 4; ++nf) {
                int brow = wn * 64 + nf * 16 + lr;
                bf16x8 bv = *(const bf16x8*)(Bs + brow * 128 + (((k2 * 4 + g) ^ (brow & 7)) << 4));
#pragma unroll
                for (int mf = 0; mf < 4; ++mf)
                    acc[mf][nf] = MFMA16(af[mf][k2], bv, acc[mf][nf]);
            }
        }
        __syncthreads();
    }
#pragma unroll
    for (int mf = 0; mf < 4; ++mf) {
        int trow = m0 + wm * 64 + mf * 16 + g * 4;
#pragma unroll
        for (int r = 0; r < 4; ++r) {
            float mv = (mask[trow + r] > 0) ? 1.0f : 0.0f;
#pragma unroll
            for (int nf = 0; nf < 4; ++nf) {
                int j = j0 + wn * 64 + nf * 16 + lr;
                out[(size_t)(trow + r) * 512 + j] = acc[mf][nf][r] * mv;
            }
        }
    }
}

// ------------------------------- launch -----------------------------------------
extern "C" void kernel_launch(void* const* d_in, const int* in_sizes, int n_in,
                              void* d_out, int out_size, void* d_ws, size_t ws_size,
                              hipStream_t stream) {
    const float* x  = (const float*)d_in[0];
    const int*  mk  = (const int*)d_in[1];
    const float* at = (const float*)d_in[2];
    const float* Wq = (const float*)d_in[3];
    const float* Wk = (const float*)d_in[4];
    const float* Wv = (const float*)d_in[5];
    const float* Wp = (const float*)d_in[6];
    float* out = (float*)d_out;
    char* ws = (char*)d_ws;

    unsigned char*  xt    = (unsigned char*)(ws);                        // [0,64) tiled x (live during k_qkv)
    float* part_pv = (float*)(ws + ((size_t)32 << 20));                  // [32,48.8) (after xt dead)
    float* part_ml = (float*)(ws + ((size_t)52 << 20));                  // [52,52.5)
    unsigned short* Kbf   = (unsigned short*)(ws + ((size_t)64 << 20));  // [64,128)
    unsigned short* Vt    = (unsigned short*)(ws + ((size_t)128 << 20)); // [128,192)
    unsigned char*  Qat   = (unsigned char*)(ws + ((size_t)192 << 20));  // [192,224) tiled q-attn
    unsigned short* Wpt   = (unsigned short*)(ws + ((size_t)256 << 20)); // [256,256.5) Wproj^T
    unsigned char*  wtl   = (unsigned char*)(ws + ((size_t)258 << 20));  // [258,259.5) tiled QKV weights
    unsigned short* abf   = (unsigned short*)(ws + ((size_t)259 << 20) + (512 << 10)); // 259.5 MiB, 32 KiB
    unsigned short* avbf  = (unsigned short*)(ws + ((size_t)259 << 20) + (576 << 10)); // +128 KiB
    unsigned char*  AVPt  = (unsigned char*)(ws + ((size_t)260 << 20));  // [260,261) tiled

    k_cvt_x<<<16384, 256, 0, stream>>>(x, xt);
    k_w_t_p<<<dim3(16, 16), 256, 0, stream>>>(Wp, Wpt);
    k_w_tile<<<dim3(8, 8, 3), 256, 0, stream>>>(Wq, Wk, Wv, wtl);
    k_pack_a<<<64, 256, 0, stream>>>(at, abf);
    k_qkv<<<4096, 256, 0, stream>>>(xt, wtl, abf, Qat, Kbf, Vt);
    k_agent_part<<<dim3(64, 32), 256, 0, stream>>>(Kbf, Vt, abf, mk, part_pv, part_ml);
    k_agent_comb<<<dim3(8, 32), 256, 0, stream>>>(part_pv, part_ml, avbf);
    k_avp<<<32, 64, 0, stream>>>(avbf, Wpt, AVPt);
    k_out<<<2048, 256, 0, stream>>>(Qat, AVPt, mk, out);
}